// Round 5
// baseline (1898.573 us; speedup 1.0000x reference)
//
#include <hip/hip_runtime.h>
#include <hip/hip_bf16.h>
#include <math.h>

typedef unsigned short u16;
typedef unsigned int   u32;
typedef unsigned long long u64;

#define DEV static __device__ __forceinline__

static constexpr int LL = 128, DD = 512, HH = 256, KK = 5, NN = 1024;

// workspace byte offsets
static constexpr size_t OFF_QP   = 0;        // 512 f32
static constexpr size_t OFF_U    = 4096;     // 512 f32
static constexpr size_t OFF_CC   = 8192;     // 1 f32
static constexpr size_t OFF_SC   = 12288;    // 1024 f32
static constexpr size_t OFF_WSC  = 16384;    // 5 f32
static constexpr size_t OFF_IDX  = 16640;    // 5 int
static constexpr size_t OFF_HG   = 20480;    // [2 layers][2 dir][2 parity][5][256] u64 = 81920B
static constexpr size_t OFF_PRE  = 102400;   // [2][128][5][1024] f32 = 5242880B
static constexpr size_t OFF_OUT0 = OFF_PRE  + (size_t)2*LL*5*1024*4;
static constexpr size_t OFF_OUT1 = OFF_OUT0 + (size_t)5*LL*DD*4;

DEV float sigf(float x){ return 1.0f/(1.0f + expf(-x)); }

// raw workgroup barrier: LDS-only drain (lgkmcnt), no vmcnt(0) store-ack
// drain. Correct here because the tagged u64 publish needs no vm ordering
// (tag travels with the data) and all intra-WG handoff is via LDS.
#define WGBAR() do { \
  asm volatile("s_waitcnt lgkmcnt(0)" ::: "memory"); \
  __builtin_amdgcn_s_barrier(); \
  __builtin_amdgcn_sched_barrier(0); \
} while (0)

// ---------------- query projection: qp = Wq @ q + bq ----------------
__global__ void k_qproj(const float* __restrict__ Wq, const float* __restrict__ q,
                        const float* __restrict__ bq, float* __restrict__ qp) {
  __shared__ float qs[512];
  int tid = threadIdx.x;
  qs[tid] = q[tid]; qs[tid+256] = q[tid+256];
  __syncthreads();
  int row  = blockIdx.x*8 + (tid >> 5);
  int lane = tid & 31;
  const float* wr = Wq + (size_t)row*512 + lane*16;
  float acc = 0.f;
  #pragma unroll
  for (int j = 0; j < 16; j += 4) {
    float4 w = *(const float4*)(wr + j);
    acc += w.x*qs[lane*16+j] + w.y*qs[lane*16+j+1] + w.z*qs[lane*16+j+2] + w.w*qs[lane*16+j+3];
  }
  #pragma unroll
  for (int off = 16; off > 0; off >>= 1) acc += __shfl_down(acc, off, 32);
  if (lane == 0) qp[row] = acc + bq[row];
}

// ---------------- u = Wk^T @ qp ; cconst = bk . qp ----------------
__global__ void k_keyvec(const float* __restrict__ Wk, const float* __restrict__ bk,
                         const float* __restrict__ qp, float* __restrict__ u,
                         float* __restrict__ cconst) {
  __shared__ float qs[512];
  __shared__ float red[16][17];
  __shared__ float r2[256];
  int tid = threadIdx.x;
  qs[tid] = qp[tid]; qs[tid+256] = qp[tid+256];
  __syncthreads();
  int cl = tid & 15;
  int jc = tid >> 4;                 // 0..15, 32 j's each
  int col = blockIdx.x*16 + cl;
  float acc = 0.f;
  for (int j = jc*32; j < jc*32 + 32; ++j) acc += Wk[(size_t)j*512 + col] * qs[j];
  red[cl][jc] = acc;
  __syncthreads();
  if (tid < 16) {
    float a = 0.f;
    #pragma unroll
    for (int m = 0; m < 16; ++m) a += red[tid][m];
    u[blockIdx.x*16 + tid] = a;
  }
  if (blockIdx.x == 0) {
    float b2 = bk[tid]*qs[tid] + bk[tid+256]*qs[tid+256];
    r2[tid] = b2;
    __syncthreads();
    for (int off = 128; off > 0; off >>= 1) { if (tid < off) r2[tid] += r2[tid+off]; __syncthreads(); }
    if (tid == 0) cconst[0] = r2[0];
  }
}

// ---------------- scores[n] = (1/L) sum_{l,d} ep[n,l,d]*u[d] + c ----------------
__global__ void k_scores(const float* __restrict__ ep, const float* __restrict__ u,
                         const float* __restrict__ cconst, float* __restrict__ scores) {
  __shared__ float red[256];
  int tid = threadIdx.x, n = blockIdx.x;
  int d0 = (tid * 4) & 511;
  float u0 = u[d0+0], u1 = u[d0+1], u2 = u[d0+2], u3 = u[d0+3];
  const float* base = ep + (size_t)n * (LL*DD);
  float acc = 0.f;
  for (int c = tid; c < (LL*DD)/4; c += 256) {
    float4 v = *(const float4*)(base + (size_t)c*4);
    acc += v.x*u0 + v.y*u1 + v.z*u2 + v.w*u3;
  }
  red[tid] = acc;
  __syncthreads();
  for (int off = 128; off > 0; off >>= 1) { if (tid < off) red[tid] += red[tid+off]; __syncthreads(); }
  if (tid == 0) scores[n] = red[0] * (1.0f/LL) + cconst[0];
}

// ---------------- top-5 + age weights ----------------
__global__ void k_topk(const float* __restrict__ scores, const float* __restrict__ ages,
                       int* __restrict__ idx5, float* __restrict__ wsc) {
  __shared__ float s0[NN];
  __shared__ float sv[NN];
  __shared__ int   si[NN];
  __shared__ int   chosen[KK];
  int tid = threadIdx.x;                 // 1024 threads
  s0[tid] = scores[tid];
  __syncthreads();
  for (int r = 0; r < KK; ++r) {
    float v = s0[tid];
    for (int m = 0; m < r; ++m) if (chosen[m] == tid) v = -3.4e38f;
    sv[tid] = v; si[tid] = tid;
    __syncthreads();
    for (int off = 512; off > 0; off >>= 1) {
      if (tid < off) {
        float a = sv[tid], b = sv[tid+off];
        int ia = si[tid], ib = si[tid+off];
        if (b > a || (b == a && ib < ia)) { sv[tid] = b; si[tid] = ib; }
      }
      __syncthreads();
    }
    if (tid == 0) {
      int w = si[0];
      chosen[r] = w;
      idx5[r] = w;
      wsc[r] = 1.0f / (1.0f + ages[w] * 0.01f);
    }
    __syncthreads();
  }
}

// ---------------- pre-projection: pre[dir][t][b][g] = x[b,t,:] . w_ih[g,:] + b_ih[g] + b_hh[g] ----------------
__global__ void k_pre(const float* __restrict__ ep, const float* __restrict__ x1,
                      const int* __restrict__ idx5, const float* __restrict__ wsc,
                      const float* __restrict__ wihF, const float* __restrict__ wihB,
                      const float* __restrict__ bihF, const float* __restrict__ bhhF,
                      const float* __restrict__ bihB, const float* __restrict__ bhhB,
                      float* __restrict__ pre) {
  int t = blockIdx.x, rb = blockIdx.y, dir = blockIdx.z;
  int tid = threadIdx.x;                 // 256 threads
  __shared__ __align__(16) float xs[5*512];
  __shared__ __align__(16) float wt[256*36];
  if (ep) {
    for (int f = tid; f < 5*512; f += 256) {
      int b = f >> 9, i = f & 511;
      xs[f] = ep[((size_t)idx5[b]*LL + t)*DD + i] * wsc[b];
    }
  } else {
    for (int f = tid; f < 5*512; f += 256) {
      int b = f >> 9, i = f & 511;
      xs[f] = x1[((size_t)b*LL + t)*DD + i];
    }
  }
  const float* wih = dir ? wihB : wihF;
  const float* bih = dir ? bihB : bihF;
  const float* bhh = dir ? bhhB : bhhF;
  int r0 = rb * 256;
  float acc[5] = {0,0,0,0,0};
  for (int it = 0; it < 16; ++it) {
    __syncthreads();
    for (int c = tid; c < 2048; c += 256) {
      int rr = c >> 3;
      int ii = (c & 7) * 4;
      *(float4*)&wt[rr*36 + ii] = *(const float4*)&wih[(size_t)(r0+rr)*512 + it*32 + ii];
    }
    __syncthreads();
    const float* wrow = &wt[(size_t)tid*36];
    const float* xb = &xs[it*32];
    for (int ii = 0; ii < 32; ii += 4) {
      float4 w = *(const float4*)(wrow + ii);
      #pragma unroll
      for (int b = 0; b < 5; ++b) {
        float4 xv = *(const float4*)&xb[b*512 + ii];
        acc[b] += w.x*xv.x + w.y*xv.y + w.z*xv.z + w.w*xv.w;
      }
    }
  }
  int grow = r0 + tid;
  float bias = bih[grow] + bhh[grow];
  size_t pbase = (((size_t)dir*LL + t)*5)*1024 + grow;
  #pragma unroll
  for (int b = 0; b < 5; ++b) pre[pbase + (size_t)b*1024] = acc[b] + bias;
}

// ---------------- persistent bidirectional LSTM layer ----------------
// ROUND-5: grid = 64 WGs x 256 thr (32 WGs/direction, 8 units each).
// Model fit from R0-R4: step time = per-CU LDS wave-instruction count x ~12cy.
// R0 (16 WGs x 1024): 640 uniform ds_read_b128/CU/step = 7680cy ~= observed.
// Here: 4 waves/CU x 40 ds_read_b128 = 160 instrs/CU/step (~1900cy), and each
// instr carries TWO distinct addresses (half-wave col chunks) = free 2-way
// bank aliasing, 32 useful B/instr instead of 16.
// thread = (r = tid&31 -> local gate row: gate=r>>3, unit=r&7;
//           jq = tid>>5 -> 32-wide col chunk). w_hh slice in VGPRs (32/thread).
// Sync: tagged u64 exchange (hi32 = step tag, lo32 = f32 bits), parity
// double-buffered per direction; proven induction: end-of-step barrier =>
// publish(s+1) implies gather(s) complete, so parity slots never overwritten
// while readable. finalize = tid<40 (no spinning); gather = tid 64..255,
// 7 concurrent slots each; pre prefetch register-carried under the spin.
__global__ __launch_bounds__(256) void k_lstm(
    const float* __restrict__ whhF, const float* __restrict__ whhB,
    const float* __restrict__ pre, float* __restrict__ out,
    u64* __restrict__ hg) {
  int wg  = blockIdx.x;                   // 64 WGs
  int dir = wg >> 5;
  int q   = wg & 31;                      // unit chunk: units [q*8, q*8+8)
  int tid = threadIdx.x;
  int r   = tid & 31;                     // local gate row (gate=r>>3, unit=r&7)
  int jq  = tid >> 5;                     // 0..7
  int jb  = jq * 32;
  const float* whh = dir ? whhB : whhF;

  __shared__ __align__(16) float h_lds[5*256];
  __shared__ float part[32*5*9];          // [r][b][jq] pad 9 = 1440 f
  __shared__ float c_s[40];
  __shared__ float pre_lds[2*160];        // [parity][b*32 + localrow]

  // weight fragment: global gate row gr, cols [jb, jb+32)
  int gr = (r >> 3) * 256 + q * 8 + (r & 7);
  float w[32];
  #pragma unroll
  for (int m4 = 0; m4 < 8; ++m4) {
    float4 a = *(const float4*)(whh + (size_t)gr*256 + jb + m4*4);
    w[m4*4+0] = a.x; w[m4*4+1] = a.y; w[m4*4+2] = a.z; w[m4*4+3] = a.w;
  }
  for (int f = tid; f < 1280; f += 256) h_lds[f] = 0.f;
  if (tid < 40) c_s[tid] = 0.f;
  u64* hg_dir = hg + (size_t)dir * 2 * 1280;

  // prologue: pre for step 0 into parity-0 buffer
  if (tid >= 64 && tid < 224) {
    int f = tid - 64;                     // 0..159
    int b = f >> 5, rr = f & 31;
    int grow = (rr >> 3)*256 + q*8 + (rr & 7);
    int t0 = dir ? (LL-1) : 0;
    pre_lds[f] = pre[(((size_t)dir*LL + t0)*5 + b)*1024 + grow];
  }
  __syncthreads();

  for (int s = 0; s < LL; ++s) {
    int par  = s & 1;
    int parn = (s + 1) & 1;
    int t = dir ? (LL-1-s) : s;
    // (A) matvec: one row x 32 cols x 5 batches, weights in registers.
    // Each b128 read carries 2 distinct addresses across the wave (jq pairs).
    {
      float acc[5] = {0.f, 0.f, 0.f, 0.f, 0.f};
      #pragma unroll
      for (int b = 0; b < 5; ++b) {
        const float4* h4 = (const float4*)&h_lds[b*256 + jb];
        #pragma unroll
        for (int m4 = 0; m4 < 8; ++m4) {
          float4 hv = h4[m4];
          acc[b] += w[m4*4+0]*hv.x + w[m4*4+1]*hv.y + w[m4*4+2]*hv.z + w[m4*4+3]*hv.w;
        }
      }
      #pragma unroll
      for (int b = 0; b < 5; ++b) part[(r*5 + b)*9 + jq] = acc[b];
    }
    WGBAR();
    // (B) finalize (tid<40) || gather (tid>=64, 7 concurrent slots) || prefetch
    if (tid < 40) {
      int b = tid >> 3, u = tid & 7;
      float g[4];
      #pragma unroll
      for (int gate = 0; gate < 4; ++gate) {
        int rr = gate*8 + u;
        float sum = pre_lds[par*160 + b*32 + rr];
        #pragma unroll
        for (int m = 0; m < 8; ++m) sum += part[(rr*5 + b)*9 + m];
        g[gate] = sum;
      }
      float ig = sigf(g[0]), fg = sigf(g[1]), cc = tanhf(g[2]), og = sigf(g[3]);
      float cn = fg * c_s[tid] + ig * cc;
      float hv = og * tanhf(cn);
      // publish first: tagged value, visibility starts asap
      u64 pk = ((u64)(u32)(s + 1) << 32) | (u64)__float_as_uint(hv);
      __hip_atomic_store(&hg_dir[(size_t)parn*1280 + b*256 + q*8 + u], pk,
                         __ATOMIC_RELAXED, __HIP_MEMORY_SCOPE_AGENT);
      c_s[tid] = cn;
      out[((size_t)b*LL + t)*DD + dir*HH + q*8 + u] = hv;
    } else if (tid >= 64) {
      // prefetch issue (register-carried; LDS store after the spin)
      float pfv = 0.f; int pfok = 0;
      if (tid < 224 && s + 1 < LL) {
        int f = tid - 64;
        int b = f >> 5, rr = f & 31;
        int grow = (rr >> 3)*256 + q*8 + (rr & 7);
        int tn = dir ? (LL-2-s) : (s+1);
        pfv = pre[(((size_t)dir*LL + tn)*5 + b)*1024 + grow];
        pfok = 1;
      }
      if (s + 1 < LL) {
        u32 sp = (u32)(s + 1);
        const u64* hrd = hg_dir + (size_t)parn * 1280;
        int f0 = tid - 64;                // 0..191, slots f0 + 192k, k<7
        u64 v[7]; bool d[7];
        #pragma unroll
        for (int k = 0; k < 7; ++k) {
          int f = f0 + 192*k;
          d[k] = (f >= 1280);
          v[k] = d[k] ? 0ull
                      : __hip_atomic_load(&hrd[f], __ATOMIC_RELAXED, __HIP_MEMORY_SCOPE_AGENT);
        }
        bool all;
        do {
          all = true;
          #pragma unroll
          for (int k = 0; k < 7; ++k) {
            if (!d[k]) {
              int f = f0 + 192*k;
              if ((u32)(v[k] >> 32) == sp) {
                h_lds[f] = __uint_as_float((u32)v[k]);
                d[k] = true;
              } else {
                v[k] = __hip_atomic_load(&hrd[f], __ATOMIC_RELAXED, __HIP_MEMORY_SCOPE_AGENT);
                all = false;
              }
            }
          }
        } while (!all);
      }
      if (pfok) pre_lds[parn*160 + (tid - 64)] = pfv;
    }
    WGBAR();
  }
}

// ---------------- attention epilogue ----------------
__global__ void k_attn(const float* __restrict__ out1, const float* __restrict__ csb,
                       float* __restrict__ outp) {
  int b = blockIdx.x, tid = threadIdx.x;   // 5 blocks x 256 threads
  __shared__ float cs[512];
  __shared__ float att[128];
  __shared__ float red[256];
  __shared__ float smax, ssum;
  cs[tid] = csb[tid]; cs[tid+256] = csb[tid+256];
  __syncthreads();
  {
    int t = tid & 127, half = tid >> 7;
    const float* row = out1 + ((size_t)b*LL + t)*DD + half*256;
    const float* c2 = cs + half*256;
    float a = 0.f;
    for (int d = 0; d < 256; ++d) a += row[d] * c2[d];
    red[tid] = a;
  }
  __syncthreads();
  if (tid < 128) att[tid] = red[tid] + red[tid+128];
  __syncthreads();
  if (tid < 64) red[tid] = fmaxf(att[tid], att[tid+64]);
  __syncthreads();
  if (tid == 0) { float m = red[0]; for (int o = 1; o < 64; ++o) m = fmaxf(m, red[o]); smax = m; }
  __syncthreads();
  if (tid < 128) att[tid] = expf(att[tid] - smax);
  __syncthreads();
  if (tid < 64) red[tid] = att[tid] + att[tid+64];
  __syncthreads();
  if (tid == 0) { float s = 0.f; for (int o = 0; o < 64; ++o) s += red[o]; ssum = s; }
  __syncthreads();
  float inv = 1.0f / ssum;
  for (int d = tid; d < DD; d += 256) {
    float acc = 0.f;
    for (int t2 = 0; t2 < LL; ++t2) acc += att[t2] * out1[((size_t)b*LL + t2)*DD + d];
    outp[b*DD + d] = acc * inv;
  }
}

extern "C" void kernel_launch(void* const* d_in, const int* in_sizes, int n_in,
                              void* d_out, int out_size, void* d_ws, size_t ws_size,
                              hipStream_t stream) {
  (void)in_sizes; (void)n_in; (void)out_size; (void)ws_size;
  const float* ep   = (const float*)d_in[0];
  const float* qu   = (const float*)d_in[1];
  const float* cst  = (const float*)d_in[2];
  const float* ages = (const float*)d_in[3];
  const float* Wq   = (const float*)d_in[4];
  const float* bq   = (const float*)d_in[5];
  const float* Wk   = (const float*)d_in[6];
  const float* bk   = (const float*)d_in[7];
  const float *wih[4], *whh[4], *bih[4], *bhh[4];
  for (int l = 0; l < 4; ++l) {
    wih[l] = (const float*)d_in[8 + l*4 + 0];
    whh[l] = (const float*)d_in[8 + l*4 + 1];
    bih[l] = (const float*)d_in[8 + l*4 + 2];
    bhh[l] = (const float*)d_in[8 + l*4 + 3];
  }
  char* ws = (char*)d_ws;
  float* qp   = (float*)(ws + OFF_QP);
  float* uvec = (float*)(ws + OFF_U);
  float* cc   = (float*)(ws + OFF_CC);
  float* sc   = (float*)(ws + OFF_SC);
  float* wsc  = (float*)(ws + OFF_WSC);
  int*   idx5 = (int*)  (ws + OFF_IDX);
  u64*   hg0  = (u64*)  (ws + OFF_HG);
  u64*   hg1  = (u64*)  (ws + OFF_HG + 40960);
  float* pre  = (float*)(ws + OFF_PRE);
  float* out0 = (float*)(ws + OFF_OUT0);
  float* out1 = (float*)(ws + OFF_OUT1);

  hipMemsetAsync(ws + OFF_HG, 0, 81920, stream);   // both layers' tagged h buffers

  k_qproj <<<64, 256, 0, stream>>>(Wq, qu, bq, qp);
  k_keyvec<<<32, 256, 0, stream>>>(Wk, bk, qp, uvec, cc);
  k_scores<<<NN, 256, 0, stream>>>(ep, uvec, cc, sc);
  k_topk  <<<1, 1024, 0, stream>>>(sc, ages, idx5, wsc);

  k_pre <<<dim3(LL,4,2), 256, 0, stream>>>(ep, nullptr, idx5, wsc,
        wih[0], wih[1], bih[0], bhh[0], bih[1], bhh[1], pre);
  k_lstm<<<64, 256, 0, stream>>>(whh[0], whh[1], pre, out0, hg0);

  k_pre <<<dim3(LL,4,2), 256, 0, stream>>>(nullptr, out0, idx5, wsc,
        wih[2], wih[3], bih[2], bhh[2], bih[3], bhh[3], pre);
  k_lstm<<<64, 256, 0, stream>>>(whh[2], whh[3], pre, out1, hg1);

  k_attn<<<KK, 256, 0, stream>>>(out1, cst, (float*)d_out);
}

// Round 6
// 1451.109 us; speedup vs baseline: 1.3084x; 1.3084x over previous
//
#include <hip/hip_runtime.h>
#include <hip/hip_bf16.h>
#include <math.h>

typedef unsigned short u16;
typedef unsigned int   u32;
typedef unsigned long long u64;

#define DEV static __device__ __forceinline__

static constexpr int LL = 128, DD = 512, HH = 256, KK = 5, NN = 1024;

// workspace byte offsets (R0 layout)
static constexpr size_t OFF_QP   = 0;        // 512 f32
static constexpr size_t OFF_U    = 4096;     // 512 f32
static constexpr size_t OFF_CC   = 8192;     // 1 f32
static constexpr size_t OFF_SC   = 12288;    // 1024 f32
static constexpr size_t OFF_WSC  = 16384;    // 5 f32
static constexpr size_t OFF_IDX  = 16640;    // 5 int
static constexpr size_t OFF_HG   = 20480;    // [2 layers][2 dir][2 parity][5][256] f32 = 40960B
static constexpr size_t OFF_FLG0 = 61440;    // layer0 flags (4KB; dir stride 256B)
static constexpr size_t OFF_FLG1 = 65536;    // layer1 flags (4KB)
static constexpr size_t OFF_PRE  = 73728;    // [2][128][5][1024] f32 = 5242880B
static constexpr size_t OFF_OUT0 = OFF_PRE  + (size_t)2*LL*5*1024*4;
static constexpr size_t OFF_OUT1 = OFF_OUT0 + (size_t)5*LL*DD*4;

DEV float sigf(float x){ return 1.0f/(1.0f + expf(-x)); }

// ---------------- query projection: qp = Wq @ q + bq ----------------
// 64 blocks x 256 thr; 8 rows/block, 32 lanes/row
__global__ void k_qproj(const float* __restrict__ Wq, const float* __restrict__ q,
                        const float* __restrict__ bq, float* __restrict__ qp) {
  __shared__ float qs[512];
  int tid = threadIdx.x;
  qs[tid] = q[tid]; qs[tid+256] = q[tid+256];
  __syncthreads();
  int row  = blockIdx.x*8 + (tid >> 5);
  int lane = tid & 31;
  const float* wr = Wq + (size_t)row*512 + lane*16;
  float acc = 0.f;
  #pragma unroll
  for (int j = 0; j < 16; j += 4) {
    float4 w = *(const float4*)(wr + j);
    acc += w.x*qs[lane*16+j] + w.y*qs[lane*16+j+1] + w.z*qs[lane*16+j+2] + w.w*qs[lane*16+j+3];
  }
  #pragma unroll
  for (int off = 16; off > 0; off >>= 1) acc += __shfl_down(acc, off, 32);
  if (lane == 0) qp[row] = acc + bq[row];
}

// ---------------- u = Wk^T @ qp ; cconst = bk . qp ----------------
// 32 blocks x 256 thr; 16 cols/block, 16 j-chunks
__global__ void k_keyvec(const float* __restrict__ Wk, const float* __restrict__ bk,
                         const float* __restrict__ qp, float* __restrict__ u,
                         float* __restrict__ cconst) {
  __shared__ float qs[512];
  __shared__ float red[16][17];
  __shared__ float r2[256];
  int tid = threadIdx.x;
  qs[tid] = qp[tid]; qs[tid+256] = qp[tid+256];
  __syncthreads();
  int cl = tid & 15;
  int jc = tid >> 4;                 // 0..15, 32 j's each
  int col = blockIdx.x*16 + cl;
  float acc = 0.f;
  for (int j = jc*32; j < jc*32 + 32; ++j) acc += Wk[(size_t)j*512 + col] * qs[j];
  red[cl][jc] = acc;
  __syncthreads();
  if (tid < 16) {
    float a = 0.f;
    #pragma unroll
    for (int m = 0; m < 16; ++m) a += red[tid][m];
    u[blockIdx.x*16 + tid] = a;
  }
  if (blockIdx.x == 0) {
    float b2 = bk[tid]*qs[tid] + bk[tid+256]*qs[tid+256];
    r2[tid] = b2;
    __syncthreads();
    for (int off = 128; off > 0; off >>= 1) { if (tid < off) r2[tid] += r2[tid+off]; __syncthreads(); }
    if (tid == 0) cconst[0] = r2[0];
  }
}

// ---------------- scores[n] = (1/L) sum_{l,d} ep[n,l,d]*u[d] + c ----------------
__global__ void k_scores(const float* __restrict__ ep, const float* __restrict__ u,
                         const float* __restrict__ cconst, float* __restrict__ scores) {
  __shared__ float red[256];
  int tid = threadIdx.x, n = blockIdx.x;
  int d0 = (tid * 4) & 511;
  float u0 = u[d0+0], u1 = u[d0+1], u2 = u[d0+2], u3 = u[d0+3];
  const float* base = ep + (size_t)n * (LL*DD);
  float acc = 0.f;
  for (int c = tid; c < (LL*DD)/4; c += 256) {
    float4 v = *(const float4*)(base + (size_t)c*4);
    acc += v.x*u0 + v.y*u1 + v.z*u2 + v.w*u3;
  }
  red[tid] = acc;
  __syncthreads();
  for (int off = 128; off > 0; off >>= 1) { if (tid < off) red[tid] += red[tid+off]; __syncthreads(); }
  if (tid == 0) scores[n] = red[0] * (1.0f/LL) + cconst[0];
}

// ---------------- top-5 + age weights ----------------
__global__ void k_topk(const float* __restrict__ scores, const float* __restrict__ ages,
                       int* __restrict__ idx5, float* __restrict__ wsc) {
  __shared__ float s0[NN];
  __shared__ float sv[NN];
  __shared__ int   si[NN];
  __shared__ int   chosen[KK];
  int tid = threadIdx.x;                 // 1024 threads
  s0[tid] = scores[tid];
  __syncthreads();
  for (int r = 0; r < KK; ++r) {
    float v = s0[tid];
    for (int m = 0; m < r; ++m) if (chosen[m] == tid) v = -3.4e38f;
    sv[tid] = v; si[tid] = tid;
    __syncthreads();
    for (int off = 512; off > 0; off >>= 1) {
      if (tid < off) {
        float a = sv[tid], b = sv[tid+off];
        int ia = si[tid], ib = si[tid+off];
        if (b > a || (b == a && ib < ia)) { sv[tid] = b; si[tid] = ib; }
      }
      __syncthreads();
    }
    if (tid == 0) {
      int w = si[0];
      chosen[r] = w;
      idx5[r] = w;
      wsc[r] = 1.0f / (1.0f + ages[w] * 0.01f);
    }
    __syncthreads();
  }
}

// ---------------- pre-projection (ROUND-6 rewrite) ----------------
// pre[dir][t][b][g] = x[b,t,:] . w_ih[g,:] + b_ih[g] + b_hh[g]
// grid (128 t, 2 dir) = 256 blocks (1/CU) x 256 thr. Thread owns 4 gate rows
// {tid, tid+256, tid+512, tid+768}; weights streamed straight from global
// (L2-resident, each row read as 128 consecutive quads = full-line use);
// x staged once in LDS (10KB) and its 5 broadcast b128 reads per k-quad are
// amortized over 4 rows (total LDS wave-instrs: 2.6M -> 0.65M per launch vs
// the old 36KB-staging design; weight staging redundancy 512MB -> 0).
__global__ __launch_bounds__(256) void k_pre(
    const float* __restrict__ ep, const float* __restrict__ x1,
    const int* __restrict__ idx5, const float* __restrict__ wsc,
    const float* __restrict__ wihF, const float* __restrict__ wihB,
    const float* __restrict__ bihF, const float* __restrict__ bhhF,
    const float* __restrict__ bihB, const float* __restrict__ bhhB,
    float* __restrict__ pre) {
  int t = blockIdx.x, dir = blockIdx.y;
  int tid = threadIdx.x;                 // 256 threads
  __shared__ __align__(16) float xs[5*512];
  if (ep) {
    for (int f = tid; f < 5*512; f += 256) {
      int b = f >> 9, i = f & 511;
      xs[f] = ep[((size_t)idx5[b]*LL + t)*DD + i] * wsc[b];
    }
  } else {
    for (int f = tid; f < 5*512; f += 256) {
      int b = f >> 9, i = f & 511;
      xs[f] = x1[((size_t)b*LL + t)*DD + i];
    }
  }
  const float* wih = dir ? wihB : wihF;
  const float* bih = dir ? bihB : bihF;
  const float* bhh = dir ? bhhB : bhhF;
  __syncthreads();

  const float4* w4 = (const float4*)wih;       // row stride = 128 quads
  const float4* x4 = (const float4*)xs;        // b stride = 128 quads
  float acc[4][5];
  #pragma unroll
  for (int g = 0; g < 4; ++g)
    #pragma unroll
    for (int b = 0; b < 5; ++b) acc[g][b] = 0.f;

  #pragma unroll 4
  for (int kq = 0; kq < 128; ++kq) {
    float4 xv[5];
    #pragma unroll
    for (int b = 0; b < 5; ++b) xv[b] = x4[b*128 + kq];
    #pragma unroll
    for (int g = 0; g < 4; ++g) {
      float4 w = w4[(size_t)(tid + g*256)*128 + kq];
      #pragma unroll
      for (int b = 0; b < 5; ++b) {
        acc[g][b] += w.x*xv[b].x + w.y*xv[b].y + w.z*xv[b].z + w.w*xv[b].w;
      }
    }
  }

  size_t pbase = (((size_t)dir*LL + t)*5)*1024;
  #pragma unroll
  for (int g = 0; g < 4; ++g) {
    int row = tid + g*256;
    float bias = bih[row] + bhh[row];
    #pragma unroll
    for (int b = 0; b < 5; ++b)
      pre[pbase + (size_t)b*1024 + row] = acc[g][b] + bias;
  }
}

// ---------------- persistent bidirectional LSTM layer (R0 champion, verbatim) ----------------
// grid = 16 WGs x 1024 thr. WG = (dir = blk>>3, unit-chunk q = blk&7, 32 units each).
// thread = (p = tid&127 -> local gate row, jq = tid>>7 -> 32-wide col chunk).
// w_hh slice in VGPRs (32 fp32/thread). Sync: per-direction flag-per-WG step
// counters (relaxed atomics; __syncthreads' vmcnt(0) drain before s_barrier
// gives release ordering). Own h chunk stays in LDS; peers gathered from IF.
__global__ __launch_bounds__(1024) void k_lstm(
    const float* __restrict__ whhF, const float* __restrict__ whhB,
    const float* __restrict__ pre, float* __restrict__ out,
    float* __restrict__ hg, int* __restrict__ flg) {
  int wg  = blockIdx.x;
  int dir = wg >> 3;
  int q   = wg & 7;                       // unit chunk: units [q*32, q*32+32)
  int tid = threadIdx.x;
  int p   = tid & 127;                    // local gate row (gate = p>>5, unit = p&31)
  int jq  = tid >> 7;                     // 0..7
  int jb  = jq * 32;
  const float* whh = dir ? whhB : whhF;

  __shared__ __align__(16) float h_lds[5*256];
  __shared__ float part[128*5*9];         // [row][b][jq] pad 9
  __shared__ float c_s[5*32];
  __shared__ float pre_lds[5*128];

  // weight fragment: global gate row gr, cols [jb, jb+32)
  int gr = (p >> 5) * 256 + q * 32 + (p & 31);
  float w[32];
  #pragma unroll
  for (int m4 = 0; m4 < 8; ++m4) {
    float4 a = *(const float4*)(whh + (size_t)gr*256 + jb + m4*4);
    w[m4*4+0] = a.x; w[m4*4+1] = a.y; w[m4*4+2] = a.z; w[m4*4+3] = a.w;
  }
  for (int f = tid; f < 1280; f += 1024) h_lds[f] = 0.f;
  if (tid < 160) c_s[tid] = 0.f;
  float* hg_dir = hg + (size_t)dir * 2 * 1280;
  int*  flg_dir = flg + dir * 64;         // 8 ints used, dirs 256B apart
  __syncthreads();

  for (int s = 0; s < LL; ++s) {
    int t = dir ? (LL-1-s) : s;
    // prefetch pre[t] for this step (hides under the flag wait)
    if (tid < 640) {
      int b = tid >> 7, r = tid & 127;
      int grow = (r >> 5)*256 + q*32 + (r & 31);
      pre_lds[tid] = pre[(((size_t)dir*LL + t)*5 + b)*1024 + grow];
    }
    if (s > 0) {
      const float* hrd = hg_dir + (size_t)(s & 1) * 1280;
      if (tid < 8) {
        while (__hip_atomic_load(&flg_dir[tid], __ATOMIC_RELAXED,
                                 __HIP_MEMORY_SCOPE_AGENT) < s) {}
      }
      __syncthreads();
      // gather 1120 peer h values (own 160 already in LDS)
      for (int f = tid; f < 1120; f += 1024) {
        int b = f / 224, w2 = f % 224;
        int c7 = w2 >> 5, u = w2 & 31;
        int pch = c7 + (c7 >= q);
        int idx = b*256 + pch*32 + u;
        h_lds[idx] = __hip_atomic_load(&hrd[idx], __ATOMIC_RELAXED,
                                       __HIP_MEMORY_SCOPE_AGENT);
      }
    }
    __syncthreads();
    // (B) one row x 32 cols x 5 batches, weights in registers
    float acc[5];
    #pragma unroll
    for (int b = 0; b < 5; ++b) {
      const float4* h4 = (const float4*)&h_lds[b*256 + jb];
      float a = 0.f;
      #pragma unroll
      for (int m4 = 0; m4 < 8; ++m4) {
        float4 hv = h4[m4];
        a += w[m4*4+0]*hv.x + w[m4*4+1]*hv.y + w[m4*4+2]*hv.z + w[m4*4+3]*hv.w;
      }
      acc[b] = a;
    }
    #pragma unroll
    for (int b = 0; b < 5; ++b) part[(p*5 + b)*9 + jq] = acc[b];
    __syncthreads();
    // (C) finalize 32 units x 5 batches
    if (tid < 160) {
      int b = tid >> 5, u = tid & 31;
      float g[4];
      #pragma unroll
      for (int gate = 0; gate < 4; ++gate) {
        int r = gate*32 + u;
        float sum = pre_lds[b*128 + r];
        #pragma unroll
        for (int m = 0; m < 8; ++m) sum += part[(r*5 + b)*9 + m];
        g[gate] = sum;
      }
      float ig = sigf(g[0]), fg = sigf(g[1]), cc = tanhf(g[2]), og = sigf(g[3]);
      float cn = fg * c_s[b*32 + u] + ig * cc;
      c_s[b*32 + u] = cn;
      float hv = og * tanhf(cn);
      out[((size_t)b*LL + t)*DD + dir*HH + q*32 + u] = hv;
      h_lds[b*256 + q*32 + u] = hv;      // own chunk for next step
      float* hwr = hg_dir + (size_t)((s + 1) & 1) * 1280;
      __hip_atomic_store(&hwr[b*256 + q*32 + u], hv,
                         __ATOMIC_RELAXED, __HIP_MEMORY_SCOPE_AGENT);
    }
    __syncthreads();   // vmcnt(0) drain before s_barrier => stores at IF
    if (tid == 0)
      __hip_atomic_store(&flg_dir[q], s + 1, __ATOMIC_RELAXED,
                         __HIP_MEMORY_SCOPE_AGENT);
  }
}

// ---------------- attention epilogue ----------------
__global__ void k_attn(const float* __restrict__ out1, const float* __restrict__ csb,
                       float* __restrict__ outp) {
  int b = blockIdx.x, tid = threadIdx.x;   // 5 blocks x 256 threads
  __shared__ float cs[512];
  __shared__ float att[128];
  __shared__ float red[256];
  __shared__ float smax, ssum;
  cs[tid] = csb[tid]; cs[tid+256] = csb[tid+256];
  __syncthreads();
  {
    int t = tid & 127, half = tid >> 7;
    const float* row = out1 + ((size_t)b*LL + t)*DD + half*256;
    const float* c2 = cs + half*256;
    float a = 0.f;
    for (int d = 0; d < 256; ++d) a += row[d] * c2[d];
    red[tid] = a;
  }
  __syncthreads();
  if (tid < 128) att[tid] = red[tid] + red[tid+128];
  __syncthreads();
  if (tid < 64) red[tid] = fmaxf(att[tid], att[tid+64]);
  __syncthreads();
  if (tid == 0) { float m = red[0]; for (int o = 1; o < 64; ++o) m = fmaxf(m, red[o]); smax = m; }
  __syncthreads();
  if (tid < 128) att[tid] = expf(att[tid] - smax);
  __syncthreads();
  if (tid < 64) red[tid] = att[tid] + att[tid+64];
  __syncthreads();
  if (tid == 0) { float s = 0.f; for (int o = 0; o < 64; ++o) s += red[o]; ssum = s; }
  __syncthreads();
  float inv = 1.0f / ssum;
  for (int d = tid; d < DD; d += 256) {
    float acc = 0.f;
    for (int t2 = 0; t2 < LL; ++t2) acc += att[t2] * out1[((size_t)b*LL + t2)*DD + d];
    outp[b*DD + d] = acc * inv;
  }
}

extern "C" void kernel_launch(void* const* d_in, const int* in_sizes, int n_in,
                              void* d_out, int out_size, void* d_ws, size_t ws_size,
                              hipStream_t stream) {
  (void)in_sizes; (void)n_in; (void)out_size; (void)ws_size;
  const float* ep   = (const float*)d_in[0];
  const float* qu   = (const float*)d_in[1];
  const float* cst  = (const float*)d_in[2];
  const float* ages = (const float*)d_in[3];
  const float* Wq   = (const float*)d_in[4];
  const float* bq   = (const float*)d_in[5];
  const float* Wk   = (const float*)d_in[6];
  const float* bk   = (const float*)d_in[7];
  const float *wih[4], *whh[4], *bih[4], *bhh[4];
  for (int l = 0; l < 4; ++l) {
    wih[l] = (const float*)d_in[8 + l*4 + 0];
    whh[l] = (const float*)d_in[8 + l*4 + 1];
    bih[l] = (const float*)d_in[8 + l*4 + 2];
    bhh[l] = (const float*)d_in[8 + l*4 + 3];
  }
  char* ws = (char*)d_ws;
  float* qp   = (float*)(ws + OFF_QP);
  float* uvec = (float*)(ws + OFF_U);
  float* cc   = (float*)(ws + OFF_CC);
  float* sc   = (float*)(ws + OFF_SC);
  float* wsc  = (float*)(ws + OFF_WSC);
  int*   idx5 = (int*)  (ws + OFF_IDX);
  float* hg0  = (float*)(ws + OFF_HG);
  float* hg1  = (float*)(ws + OFF_HG + 20480);
  int*   flg0 = (int*)  (ws + OFF_FLG0);
  int*   flg1 = (int*)  (ws + OFF_FLG1);
  float* pre  = (float*)(ws + OFF_PRE);
  float* out0 = (float*)(ws + OFF_OUT0);
  float* out1 = (float*)(ws + OFF_OUT1);

  hipMemsetAsync(ws + OFF_FLG0, 0, 8192, stream);   // both layers' flags

  k_qproj <<<64, 256, 0, stream>>>(Wq, qu, bq, qp);
  k_keyvec<<<32, 256, 0, stream>>>(Wk, bk, qp, uvec, cc);
  k_scores<<<NN, 256, 0, stream>>>(ep, uvec, cc, sc);
  k_topk  <<<1, 1024, 0, stream>>>(sc, ages, idx5, wsc);

  k_pre <<<dim3(LL,2), 256, 0, stream>>>(ep, nullptr, idx5, wsc,
        wih[0], wih[1], bih[0], bhh[0], bih[1], bhh[1], pre);
  k_lstm<<<16, 1024, 0, stream>>>(whh[0], whh[1], pre, out0, hg0, flg0);

  k_pre <<<dim3(LL,2), 256, 0, stream>>>(nullptr, out0, idx5, wsc,
        wih[2], wih[3], bih[2], bhh[2], bih[3], bhh[3], pre);
  k_lstm<<<16, 1024, 0, stream>>>(whh[2], whh[3], pre, out1, hg1, flg1);

  k_attn<<<KK, 256, 0, stream>>>(out1, cst, (float*)d_out);
}

// Round 7
// 1434.816 us; speedup vs baseline: 1.3232x; 1.0114x over previous
//
#include <hip/hip_runtime.h>
#include <hip/hip_bf16.h>
#include <math.h>

typedef unsigned short u16;
typedef unsigned int   u32;
typedef unsigned long long u64;

#define DEV static __device__ __forceinline__

static constexpr int LL = 128, DD = 512, HH = 256, KK = 5, NN = 1024;

// workspace byte offsets (R0 layout)
static constexpr size_t OFF_QP   = 0;        // 512 f32
static constexpr size_t OFF_U    = 4096;     // 512 f32
static constexpr size_t OFF_CC   = 8192;     // 1 f32
static constexpr size_t OFF_SC   = 12288;    // 1024 f32
static constexpr size_t OFF_WSC  = 16384;    // 5 f32
static constexpr size_t OFF_IDX  = 16640;    // 5 int
static constexpr size_t OFF_HG   = 20480;    // [2 layers][2 dir][2 parity][5][256] f32 = 40960B
static constexpr size_t OFF_FLG0 = 61440;    // layer0 flags (4KB; dir stride 256B)
static constexpr size_t OFF_FLG1 = 65536;    // layer1 flags (4KB)
static constexpr size_t OFF_PRE  = 73728;    // [2][128][5][1024] f32 = 5242880B
static constexpr size_t OFF_OUT0 = OFF_PRE  + (size_t)2*LL*5*1024*4;
static constexpr size_t OFF_OUT1 = OFF_OUT0 + (size_t)5*LL*DD*4;

DEV float sigf(float x){ return 1.0f/(1.0f + expf(-x)); }

// ---------------- query projection: qp = Wq @ q + bq ----------------
__global__ void k_qproj(const float* __restrict__ Wq, const float* __restrict__ q,
                        const float* __restrict__ bq, float* __restrict__ qp) {
  __shared__ float qs[512];
  int tid = threadIdx.x;
  qs[tid] = q[tid]; qs[tid+256] = q[tid+256];
  __syncthreads();
  int row  = blockIdx.x*8 + (tid >> 5);
  int lane = tid & 31;
  const float* wr = Wq + (size_t)row*512 + lane*16;
  float acc = 0.f;
  #pragma unroll
  for (int j = 0; j < 16; j += 4) {
    float4 w = *(const float4*)(wr + j);
    acc += w.x*qs[lane*16+j] + w.y*qs[lane*16+j+1] + w.z*qs[lane*16+j+2] + w.w*qs[lane*16+j+3];
  }
  #pragma unroll
  for (int off = 16; off > 0; off >>= 1) acc += __shfl_down(acc, off, 32);
  if (lane == 0) qp[row] = acc + bq[row];
}

// ---------------- u = Wk^T @ qp ; cconst = bk . qp ----------------
__global__ void k_keyvec(const float* __restrict__ Wk, const float* __restrict__ bk,
                         const float* __restrict__ qp, float* __restrict__ u,
                         float* __restrict__ cconst) {
  __shared__ float qs[512];
  __shared__ float red[16][17];
  __shared__ float r2[256];
  int tid = threadIdx.x;
  qs[tid] = qp[tid]; qs[tid+256] = qp[tid+256];
  __syncthreads();
  int cl = tid & 15;
  int jc = tid >> 4;                 // 0..15, 32 j's each
  int col = blockIdx.x*16 + cl;
  float acc = 0.f;
  for (int j = jc*32; j < jc*32 + 32; ++j) acc += Wk[(size_t)j*512 + col] * qs[j];
  red[cl][jc] = acc;
  __syncthreads();
  if (tid < 16) {
    float a = 0.f;
    #pragma unroll
    for (int m = 0; m < 16; ++m) a += red[tid][m];
    u[blockIdx.x*16 + tid] = a;
  }
  if (blockIdx.x == 0) {
    float b2 = bk[tid]*qs[tid] + bk[tid+256]*qs[tid+256];
    r2[tid] = b2;
    __syncthreads();
    for (int off = 128; off > 0; off >>= 1) { if (tid < off) r2[tid] += r2[tid+off]; __syncthreads(); }
    if (tid == 0) cconst[0] = r2[0];
  }
}

// ---------------- scores[n] = (1/L) sum_{l,d} ep[n,l,d]*u[d] + c ----------------
__global__ void k_scores(const float* __restrict__ ep, const float* __restrict__ u,
                         const float* __restrict__ cconst, float* __restrict__ scores) {
  __shared__ float red[256];
  int tid = threadIdx.x, n = blockIdx.x;
  int d0 = (tid * 4) & 511;
  float u0 = u[d0+0], u1 = u[d0+1], u2 = u[d0+2], u3 = u[d0+3];
  const float* base = ep + (size_t)n * (LL*DD);
  float acc = 0.f;
  for (int c = tid; c < (LL*DD)/4; c += 256) {
    float4 v = *(const float4*)(base + (size_t)c*4);
    acc += v.x*u0 + v.y*u1 + v.z*u2 + v.w*u3;
  }
  red[tid] = acc;
  __syncthreads();
  for (int off = 128; off > 0; off >>= 1) { if (tid < off) red[tid] += red[tid+off]; __syncthreads(); }
  if (tid == 0) scores[n] = red[0] * (1.0f/LL) + cconst[0];
}

// ---------------- top-5 + age weights ----------------
__global__ void k_topk(const float* __restrict__ scores, const float* __restrict__ ages,
                       int* __restrict__ idx5, float* __restrict__ wsc) {
  __shared__ float s0[NN];
  __shared__ float sv[NN];
  __shared__ int   si[NN];
  __shared__ int   chosen[KK];
  int tid = threadIdx.x;                 // 1024 threads
  s0[tid] = scores[tid];
  __syncthreads();
  for (int r = 0; r < KK; ++r) {
    float v = s0[tid];
    for (int m = 0; m < r; ++m) if (chosen[m] == tid) v = -3.4e38f;
    sv[tid] = v; si[tid] = tid;
    __syncthreads();
    for (int off = 512; off > 0; off >>= 1) {
      if (tid < off) {
        float a = sv[tid], b = sv[tid+off];
        int ia = si[tid], ib = si[tid+off];
        if (b > a || (b == a && ib < ia)) { sv[tid] = b; si[tid] = ib; }
      }
      __syncthreads();
    }
    if (tid == 0) {
      int w = si[0];
      chosen[r] = w;
      idx5[r] = w;
      wsc[r] = 1.0f / (1.0f + ages[w] * 0.01f);
    }
    __syncthreads();
  }
}

// ---------------- pre-projection (R6 winner, unchanged) ----------------
__global__ __launch_bounds__(256) void k_pre(
    const float* __restrict__ ep, const float* __restrict__ x1,
    const int* __restrict__ idx5, const float* __restrict__ wsc,
    const float* __restrict__ wihF, const float* __restrict__ wihB,
    const float* __restrict__ bihF, const float* __restrict__ bhhF,
    const float* __restrict__ bihB, const float* __restrict__ bhhB,
    float* __restrict__ pre) {
  int t = blockIdx.x, dir = blockIdx.y;
  int tid = threadIdx.x;                 // 256 threads
  __shared__ __align__(16) float xs[5*512];
  if (ep) {
    for (int f = tid; f < 5*512; f += 256) {
      int b = f >> 9, i = f & 511;
      xs[f] = ep[((size_t)idx5[b]*LL + t)*DD + i] * wsc[b];
    }
  } else {
    for (int f = tid; f < 5*512; f += 256) {
      int b = f >> 9, i = f & 511;
      xs[f] = x1[((size_t)b*LL + t)*DD + i];
    }
  }
  const float* wih = dir ? wihB : wihF;
  const float* bih = dir ? bihB : bihF;
  const float* bhh = dir ? bhhB : bhhF;
  __syncthreads();

  const float4* w4 = (const float4*)wih;       // row stride = 128 quads
  const float4* x4 = (const float4*)xs;        // b stride = 128 quads
  float acc[4][5];
  #pragma unroll
  for (int g = 0; g < 4; ++g)
    #pragma unroll
    for (int b = 0; b < 5; ++b) acc[g][b] = 0.f;

  #pragma unroll 4
  for (int kq = 0; kq < 128; ++kq) {
    float4 xv[5];
    #pragma unroll
    for (int b = 0; b < 5; ++b) xv[b] = x4[b*128 + kq];
    #pragma unroll
    for (int g = 0; g < 4; ++g) {
      float4 w = w4[(size_t)(tid + g*256)*128 + kq];
      #pragma unroll
      for (int b = 0; b < 5; ++b) {
        acc[g][b] += w.x*xv[b].x + w.y*xv[b].y + w.z*xv[b].z + w.w*xv[b].w;
      }
    }
  }

  size_t pbase = (((size_t)dir*LL + t)*5)*1024;
  #pragma unroll
  for (int g = 0; g < 4; ++g) {
    int row = tid + g*256;
    float bias = bih[row] + bhh[row];
    #pragma unroll
    for (int b = 0; b < 5; ++b)
      pre[pbase + (size_t)b*1024 + row] = acc[g][b] + bias;
  }
}

// ---------------- persistent bidirectional LSTM layer ----------------
// R0 champion topology EXACTLY (16 WGs x 1024 thr, flag sync, same gather,
// same finalize epilogue). ROUND-7 change: 2 gate-rows per thread so each
// uniform h-read feeds TWO rows' FMAs -> per-CU ds_read_b128 count halves
// (640 -> 320/step), which is the quantity that fits R0's 7900cy step time.
// thread = (rp = tid&63 -> local rows 2rp,2rp+1; jq = tid>>6 -> 16-col chunk).
// part[] layout [b][jq][130 rows] so the pair writes one b64 (stride 8B
// across lanes = free 2-way); finalize sums 16 partials (was 8).
__global__ __launch_bounds__(1024) void k_lstm(
    const float* __restrict__ whhF, const float* __restrict__ whhB,
    const float* __restrict__ pre, float* __restrict__ out,
    float* __restrict__ hg, int* __restrict__ flg) {
  int wg  = blockIdx.x;
  int dir = wg >> 3;
  int q   = wg & 7;                       // unit chunk: units [q*32, q*32+32)
  int tid = threadIdx.x;
  int rp  = tid & 63;                     // row pair: local gate rows 2rp, 2rp+1
  int jq  = tid >> 6;                     // 0..15
  int jb  = jq * 16;
  const float* whh = dir ? whhB : whhF;

  __shared__ __align__(16) float h_lds[5*256];
  __shared__ __align__(16) float part[5*16*130];   // [b][jq][130] = 41.6KB
  __shared__ float c_s[5*32];
  __shared__ float pre_lds[5*128];

  // weight fragments: two consecutive local rows, cols [jb, jb+16)
  int r0 = 2*rp, r1 = 2*rp + 1;
  int gr0 = (r0 >> 5)*256 + q*32 + (r0 & 31);
  int gr1 = (r1 >> 5)*256 + q*32 + (r1 & 31);
  float w0[16], w1[16];
  #pragma unroll
  for (int m4 = 0; m4 < 4; ++m4) {
    float4 a = *(const float4*)(whh + (size_t)gr0*256 + jb + m4*4);
    w0[m4*4+0]=a.x; w0[m4*4+1]=a.y; w0[m4*4+2]=a.z; w0[m4*4+3]=a.w;
    float4 c = *(const float4*)(whh + (size_t)gr1*256 + jb + m4*4);
    w1[m4*4+0]=c.x; w1[m4*4+1]=c.y; w1[m4*4+2]=c.z; w1[m4*4+3]=c.w;
  }
  for (int f = tid; f < 1280; f += 1024) h_lds[f] = 0.f;
  if (tid < 160) c_s[tid] = 0.f;
  float* hg_dir = hg + (size_t)dir * 2 * 1280;
  int*  flg_dir = flg + dir * 64;         // 8 ints used, dirs 256B apart
  __syncthreads();

  for (int s = 0; s < LL; ++s) {
    int t = dir ? (LL-1-s) : s;
    // prefetch pre[t] for this step (hides under the flag wait)
    if (tid < 640) {
      int b = tid >> 7, r = tid & 127;
      int grow = (r >> 5)*256 + q*32 + (r & 31);
      pre_lds[tid] = pre[(((size_t)dir*LL + t)*5 + b)*1024 + grow];
    }
    if (s > 0) {
      const float* hrd = hg_dir + (size_t)(s & 1) * 1280;
      if (tid < 8) {
        while (__hip_atomic_load(&flg_dir[tid], __ATOMIC_RELAXED,
                                 __HIP_MEMORY_SCOPE_AGENT) < s) {}
      }
      __syncthreads();
      // gather 1120 peer h values (own 160 already in LDS)
      for (int f = tid; f < 1120; f += 1024) {
        int b = f / 224, w2 = f % 224;
        int c7 = w2 >> 5, u = w2 & 31;
        int pch = c7 + (c7 >= q);
        int idx = b*256 + pch*32 + u;
        h_lds[idx] = __hip_atomic_load(&hrd[idx], __ATOMIC_RELAXED,
                                       __HIP_MEMORY_SCOPE_AGENT);
      }
    }
    __syncthreads();
    // (B) matvec: 2 rows x 16 cols x 5 batches; each uniform b128 h-read
    // feeds both rows (per-CU read instrs halved vs R0)
    {
      float acc0[5], acc1[5];
      #pragma unroll
      for (int b = 0; b < 5; ++b) {
        const float4* h4 = (const float4*)&h_lds[b*256 + jb];
        float a0 = 0.f, a1 = 0.f;
        #pragma unroll
        for (int m4 = 0; m4 < 4; ++m4) {
          float4 hv = h4[m4];
          a0 += w0[m4*4+0]*hv.x + w0[m4*4+1]*hv.y + w0[m4*4+2]*hv.z + w0[m4*4+3]*hv.w;
          a1 += w1[m4*4+0]*hv.x + w1[m4*4+1]*hv.y + w1[m4*4+2]*hv.z + w1[m4*4+3]*hv.w;
        }
        acc0[b] = a0; acc1[b] = a1;
      }
      #pragma unroll
      for (int b = 0; b < 5; ++b) {
        *(float2*)&part[(b*16 + jq)*130 + 2*rp] = make_float2(acc0[b], acc1[b]);
      }
    }
    __syncthreads();
    // (C) finalize 32 units x 5 batches (16 partials per row)
    if (tid < 160) {
      int b = tid >> 5, u = tid & 31;
      float g[4];
      #pragma unroll
      for (int gate = 0; gate < 4; ++gate) {
        int r = gate*32 + u;
        float sum = pre_lds[b*128 + r];
        #pragma unroll
        for (int m = 0; m < 16; ++m) sum += part[(b*16 + m)*130 + r];
        g[gate] = sum;
      }
      float ig = sigf(g[0]), fg = sigf(g[1]), cc = tanhf(g[2]), og = sigf(g[3]);
      float cn = fg * c_s[b*32 + u] + ig * cc;
      c_s[b*32 + u] = cn;
      float hv = og * tanhf(cn);
      out[((size_t)b*LL + t)*DD + dir*HH + q*32 + u] = hv;
      h_lds[b*256 + q*32 + u] = hv;      // own chunk for next step
      float* hwr = hg_dir + (size_t)((s + 1) & 1) * 1280;
      __hip_atomic_store(&hwr[b*256 + q*32 + u], hv,
                         __ATOMIC_RELAXED, __HIP_MEMORY_SCOPE_AGENT);
    }
    __syncthreads();   // vmcnt(0) drain before s_barrier => stores at IF
    if (tid == 0)
      __hip_atomic_store(&flg_dir[q], s + 1, __ATOMIC_RELAXED,
                         __HIP_MEMORY_SCOPE_AGENT);
  }
}

// ---------------- attention epilogue ----------------
__global__ void k_attn(const float* __restrict__ out1, const float* __restrict__ csb,
                       float* __restrict__ outp) {
  int b = blockIdx.x, tid = threadIdx.x;   // 5 blocks x 256 threads
  __shared__ float cs[512];
  __shared__ float att[128];
  __shared__ float red[256];
  __shared__ float smax, ssum;
  cs[tid] = csb[tid]; cs[tid+256] = csb[tid+256];
  __syncthreads();
  {
    int t = tid & 127, half = tid >> 7;
    const float* row = out1 + ((size_t)b*LL + t)*DD + half*256;
    const float* c2 = cs + half*256;
    float a = 0.f;
    for (int d = 0; d < 256; ++d) a += row[d] * c2[d];
    red[tid] = a;
  }
  __syncthreads();
  if (tid < 128) att[tid] = red[tid] + red[tid+128];
  __syncthreads();
  if (tid < 64) red[tid] = fmaxf(att[tid], att[tid+64]);
  __syncthreads();
  if (tid == 0) { float m = red[0]; for (int o = 1; o < 64; ++o) m = fmaxf(m, red[o]); smax = m; }
  __syncthreads();
  if (tid < 128) att[tid] = expf(att[tid] - smax);
  __syncthreads();
  if (tid < 64) red[tid] = att[tid] + att[tid+64];
  __syncthreads();
  if (tid == 0) { float s = 0.f; for (int o = 0; o < 64; ++o) s += red[o]; ssum = s; }
  __syncthreads();
  float inv = 1.0f / ssum;
  for (int d = tid; d < DD; d += 256) {
    float acc = 0.f;
    for (int t2 = 0; t2 < LL; ++t2) acc += att[t2] * out1[((size_t)b*LL + t2)*DD + d];
    outp[b*DD + d] = acc * inv;
  }
}

extern "C" void kernel_launch(void* const* d_in, const int* in_sizes, int n_in,
                              void* d_out, int out_size, void* d_ws, size_t ws_size,
                              hipStream_t stream) {
  (void)in_sizes; (void)n_in; (void)out_size; (void)ws_size;
  const float* ep   = (const float*)d_in[0];
  const float* qu   = (const float*)d_in[1];
  const float* cst  = (const float*)d_in[2];
  const float* ages = (const float*)d_in[3];
  const float* Wq   = (const float*)d_in[4];
  const float* bq   = (const float*)d_in[5];
  const float* Wk   = (const float*)d_in[6];
  const float* bk   = (const float*)d_in[7];
  const float *wih[4], *whh[4], *bih[4], *bhh[4];
  for (int l = 0; l < 4; ++l) {
    wih[l] = (const float*)d_in[8 + l*4 + 0];
    whh[l] = (const float*)d_in[8 + l*4 + 1];
    bih[l] = (const float*)d_in[8 + l*4 + 2];
    bhh[l] = (const float*)d_in[8 + l*4 + 3];
  }
  char* ws = (char*)d_ws;
  float* qp   = (float*)(ws + OFF_QP);
  float* uvec = (float*)(ws + OFF_U);
  float* cc   = (float*)(ws + OFF_CC);
  float* sc   = (float*)(ws + OFF_SC);
  float* wsc  = (float*)(ws + OFF_WSC);
  int*   idx5 = (int*)  (ws + OFF_IDX);
  float* hg0  = (float*)(ws + OFF_HG);
  float* hg1  = (float*)(ws + OFF_HG + 20480);
  int*   flg0 = (int*)  (ws + OFF_FLG0);
  int*   flg1 = (int*)  (ws + OFF_FLG1);
  float* pre  = (float*)(ws + OFF_PRE);
  float* out0 = (float*)(ws + OFF_OUT0);
  float* out1 = (float*)(ws + OFF_OUT1);

  hipMemsetAsync(ws + OFF_FLG0, 0, 8192, stream);   // both layers' flags

  k_qproj <<<64, 256, 0, stream>>>(Wq, qu, bq, qp);
  k_keyvec<<<32, 256, 0, stream>>>(Wk, bk, qp, uvec, cc);
  k_scores<<<NN, 256, 0, stream>>>(ep, uvec, cc, sc);
  k_topk  <<<1, 1024, 0, stream>>>(sc, ages, idx5, wsc);

  k_pre <<<dim3(LL,2), 256, 0, stream>>>(ep, nullptr, idx5, wsc,
        wih[0], wih[1], bih[0], bhh[0], bih[1], bhh[1], pre);
  k_lstm<<<16, 1024, 0, stream>>>(whh[0], whh[1], pre, out0, hg0, flg0);

  k_pre <<<dim3(LL,2), 256, 0, stream>>>(nullptr, out0, idx5, wsc,
        wih[2], wih[3], bih[2], bhh[2], bih[3], bhh[3], pre);
  k_lstm<<<16, 1024, 0, stream>>>(whh[2], whh[3], pre, out1, hg1, flg1);

  k_attn<<<KK, 256, 0, stream>>>(out1, cst, (float*)d_out);
}